// Round 5
// baseline (506.079 us; speedup 1.0000x reference)
//
#include <hip/hip_runtime.h>

// B=1024, N=256, F=63, D=64. Only node-0 readout matters:
//   out = (x[:,0] + y[:,0]) @ wf + bf
// v5: worklist decomposition. K1 compacts (b, j, a0j) pairs for node-0's
// neighbors into a global worklist (~14K entries) and zeroes accumulators.
// K2 processes ONE PAIR PER WAVE (grid-stride, no barriers): sparse ballot
// gather for agg_j, 63-step shfl chain for layer-1, atomicAdd into accY[b].
// K3 does layer-2 row 0 + head. All f32. TLP (8192 waves) hides all latency
// that v4's per-block serial neighbor loops could not.

#define NB 1024
#define NN 256
#define FD 63
#define DM 64

// d_ws layout (bytes)
#define OFF_CNT   0
#define OFF_ACC   1024
#define OFF_X0    (OFF_ACC + NB * DM * 4)          // 263168
#define OFF_ENT   (OFF_X0 + NB * DM * 4)           // 525312
#define OFF_A0    (OFF_ENT + NB * NN * 4)          // 1573888

__global__ void k1_build(const float* __restrict__ adj,
                         int* __restrict__ g_cnt,
                         int* __restrict__ ents,
                         float* __restrict__ a0s,
                         float* __restrict__ accY)
{
    __shared__ int   s_cnt, s_base;
    __shared__ int   s_j[NN];
    __shared__ float s_a[NN];
    const int b = blockIdx.x, t = threadIdx.x;
    if (t == 0) s_cnt = 0;
    if (t < DM) accY[b * DM + t] = 0.f;            // zero accumulators (ws is poisoned)
    __syncthreads();
    const float a = adj[(size_t)b * NN * NN + t];  // adj[b,0,t]
    if (a != 0.f) {
        int i = atomicAdd(&s_cnt, 1);
        s_j[i] = t; s_a[i] = a;
    }
    __syncthreads();
    if (t == 0) s_base = atomicAdd(g_cnt, s_cnt);
    __syncthreads();
    if (t < s_cnt) {
        ents[s_base + t] = (b << 8) | s_j[t];
        a0s[s_base + t]  = s_a[t];
    }
}

__launch_bounds__(256, 4)
__global__ void k2_pairs(const float* __restrict__ adj,
                         const float* __restrict__ vec,
                         const float* __restrict__ w1_rel,
                         const float* __restrict__ w1_root,
                         const float* __restrict__ b1,
                         const int* __restrict__ g_cnt,
                         const int* __restrict__ ents,
                         const float* __restrict__ a0s,
                         float* __restrict__ accY,
                         float* __restrict__ x0)
{
    __shared__ float s_w1rel[FD * DM];             // 15.75 KB
    __shared__ float s_w1root[FD * DM];            // 15.75 KB
    {   // coalesced float4 staging of layer-1 weights
        const float4* wr = (const float4*)w1_rel;
        const float4* wo = (const float4*)w1_root;
        float4* sr = (float4*)s_w1rel;
        float4* so = (float4*)s_w1root;
        for (int i = threadIdx.x; i < FD * DM / 4; i += 256) { sr[i] = wr[i]; so[i] = wo[i]; }
    }
    __syncthreads();

    const int lane = threadIdx.x & 63;
    const int w    = threadIdx.x >> 6;
    const int total = *g_cnt;
    const float rb1 = b1[lane];

    for (int e = blockIdx.x * 4 + w; e < total; e += gridDim.x * 4) {
        const int   pe = ents[e];
        const int   b  = pe >> 8;
        const int   j  = pe & 255;
        const float a0 = a0s[e];
        const float* adj_b = adj + (size_t)b * NN * NN;
        const float* vec_b = vec + (size_t)b * NN * FD;

        // adj row j: 4 independent 256B chunk loads
        const float* rp = adj_b + j * NN;
        const float c0 = rp[lane], c1 = rp[64 + lane], c2 = rp[128 + lane], c3 = rp[192 + lane];
        unsigned long long m0 = __ballot(c0 != 0.f), m1 = __ballot(c1 != 0.f);
        unsigned long long m2 = __ballot(c2 != 0.f), m3 = __ballot(c3 != 0.f);

        // sparse gather: agg[f=lane] = sum_k a_jk * vec[k][f]  (4 indep partials)
        float g0 = 0.f, g1 = 0.f, g2 = 0.f, g3 = 0.f;
        const bool fok = (lane < FD);
        while (m0) { int bb = __builtin_ctzll(m0); m0 &= m0 - 1;
                     float av = __shfl(c0, bb);
                     if (fok) g0 += av * vec_b[bb * FD + lane]; }
        while (m1) { int bb = __builtin_ctzll(m1); m1 &= m1 - 1;
                     float av = __shfl(c1, bb);
                     if (fok) g1 += av * vec_b[(64 + bb) * FD + lane]; }
        while (m2) { int bb = __builtin_ctzll(m2); m2 &= m2 - 1;
                     float av = __shfl(c2, bb);
                     if (fok) g2 += av * vec_b[(128 + bb) * FD + lane]; }
        while (m3) { int bb = __builtin_ctzll(m3); m3 &= m3 - 1;
                     float av = __shfl(c3, bb);
                     if (fok) g3 += av * vec_b[(192 + bb) * FD + lane]; }
        const float agg = (g0 + g1) + (g2 + g3);
        const float vj  = fok ? vec_b[j * FD + lane] : 0.f;

        // layer 1: x[d=lane] = relu(agg @ w1_rel + vec_j @ w1_root + b1)
        float accR = 0.f, accO = 0.f;
        #pragma unroll
        for (int ff = 0; ff < FD; ++ff) {
            accR += __shfl(agg, ff) * s_w1rel[ff * DM + lane];
            accO += __shfl(vj,  ff) * s_w1root[ff * DM + lane];
        }
        const float x = fmaxf(accR + accO + rb1, 0.f);

        atomicAdd(&accY[b * DM + lane], a0 * x);   // ~14 adds/address, f32, device scope
        if (j == 0) x0[b * DM + lane] = x;         // exactly one writer per b (self-loop)
    }
}

__global__ void k3_head(const float* __restrict__ accY,
                        const float* __restrict__ x0,
                        const float* __restrict__ w2_rel,
                        const float* __restrict__ w2_root,
                        const float* __restrict__ b2,
                        const float* __restrict__ wf,
                        const float* __restrict__ bf,
                        float* __restrict__ out)
{
    const int b = blockIdx.x, l = threadIdx.x;     // 64 threads = 1 wave
    const float ay  = accY[b * DM + l];
    const float x0v = x0[b * DM + l];
    float acc = 0.f;
    #pragma unroll
    for (int ff = 0; ff < DM; ++ff) {
        acc += __shfl(ay,  ff) * w2_rel[ff * DM + l]     // L2-broadcast
             + __shfl(x0v, ff) * w2_root[ff * DM + l];
    }
    const float y = fmaxf(acc + b2[l], 0.f);
    const float r = x0v + y;                        // x0 + y0
    float p0 = r * wf[l * 2], p1 = r * wf[l * 2 + 1];
    #pragma unroll
    for (int off = 32; off; off >>= 1) {
        p0 += __shfl_down(p0, off);
        p1 += __shfl_down(p1, off);
    }
    if (l == 0) {
        out[b * 2]     = p0 + bf[0];
        out[b * 2 + 1] = p1 + bf[1];
    }
}

extern "C" void kernel_launch(void* const* d_in, const int* in_sizes, int n_in,
                              void* d_out, int out_size, void* d_ws, size_t ws_size,
                              hipStream_t stream) {
    const float* adj     = (const float*)d_in[0];
    const float* vec     = (const float*)d_in[1];
    const float* w1_rel  = (const float*)d_in[2];
    const float* w1_root = (const float*)d_in[3];
    const float* b1      = (const float*)d_in[4];
    const float* w2_rel  = (const float*)d_in[5];
    const float* w2_root = (const float*)d_in[6];
    const float* b2      = (const float*)d_in[7];
    const float* wf      = (const float*)d_in[8];
    const float* bf      = (const float*)d_in[9];
    float* out = (float*)d_out;

    char* ws = (char*)d_ws;
    int*   g_cnt = (int*)  (ws + OFF_CNT);
    float* accY  = (float*)(ws + OFF_ACC);
    float* x0    = (float*)(ws + OFF_X0);
    int*   ents  = (int*)  (ws + OFF_ENT);
    float* a0s   = (float*)(ws + OFF_A0);

    hipMemsetAsync(g_cnt, 0, 64, stream);          // zero worklist counter (capturable)
    k1_build<<<NB, NN, 0, stream>>>(adj, g_cnt, ents, a0s, accY);
    k2_pairs<<<2048, 256, 0, stream>>>(adj, vec, w1_rel, w1_root, b1,
                                       g_cnt, ents, a0s, accY, x0);
    k3_head<<<NB, DM, 0, stream>>>(accY, x0, w2_rel, w2_root, b2, wf, bf, out);
}

// Round 6
// 447.540 us; speedup vs baseline: 1.1308x; 1.1308x over previous
//
#include <hip/hip_runtime.h>

// B=1024, N=256, F=63, D=64. Only node-0 readout matters:
//   out = (x[:,0] + y[:,0]) @ wf + bf
// v6: single kernel, one block per batch, 4 waves split node-0's ~14 neighbors.
// Fixes vs v4/v5: (a) NO dependent-chain gathers — per neighbor row we do an
// in-register rank-select (lane l finds its l-th set bit of the 256-bit row
// mask) then gather vec rows in UNROLLED batches of 8 independent loads (deep
// MLP, HBM-throughput-bound); (b) no vec LDS tile / no union phase -> LDS =
// w1 only (34 KB) -> 4 blocks/CU, 16 waves/CU; (c) no global atomics (v5's
// 170 MB write-amplification); (d) all f32.

#define NB 1024
#define NN 256
#define FD 63
#define DM 64
#define MAXNBR 64

__launch_bounds__(256, 4)
__global__ void gnn_node0_fused(const float* __restrict__ adj,
                                const float* __restrict__ vec,
                                const float* __restrict__ w1_rel,
                                const float* __restrict__ w1_root,
                                const float* __restrict__ b1,
                                const float* __restrict__ w2_rel,
                                const float* __restrict__ w2_root,
                                const float* __restrict__ b2,
                                const float* __restrict__ wf,
                                const float* __restrict__ bf,
                                float* __restrict__ out)
{
    __shared__ float s_w1rel[FD * DM];    // 15.75 KB
    __shared__ float s_w1root[FD * DM];   // 15.75 KB
    __shared__ int   s_nbr[MAXNBR];
    __shared__ float s_a0[MAXNBR];
    __shared__ float s_pA[4][DM], s_pB[4][DM];
    __shared__ float s_rA[DM], s_rB[DM], s_r[DM];
    __shared__ int   s_cnt;

    const int b    = blockIdx.x;
    const int t    = threadIdx.x;
    const int lane = t & 63;
    const int q    = t >> 6;
    const float* adj_b = adj + (size_t)b * NN * NN;
    const float* vec_b = vec + (size_t)b * NN * FD;

    if (t == 0) s_cnt = 0;
    __syncthreads();

    // ---- node-0 neighbor compaction (unordered; accumulation commutes)
    {
        float a = adj_b[t];
        if (a != 0.f) {
            int i = atomicAdd(&s_cnt, 1);
            if (i < MAXNBR) { s_nbr[i] = t; s_a0[i] = a; }
        }
    }
    // ---- stage w1 to LDS, f32, float4-coalesced (L2-resident across blocks)
    {
        const float4* wr = (const float4*)w1_rel;
        const float4* wo = (const float4*)w1_root;
        float4* sr = (float4*)s_w1rel;
        float4* so = (float4*)s_w1root;
        for (int i = t; i < FD * DM / 4; i += 256) { sr[i] = wr[i]; so[i] = wo[i]; }
    }
    __syncthreads();

    const int   cnt = min(s_cnt, MAXNBR);   // >=1 (self-loop at node 0)
    const float rb1 = b1[lane];
    const bool  fok = (lane < FD);

    float accY = 0.f, x0r = 0.f;

    // ---- wave q owns neighbors i = q, q+4, ...; no barriers inside.
    for (int i = q; i < cnt; i += 4) {
        const int   j  = s_nbr[i];
        const float a0 = s_a0[i];

        // vec row j (layer-1 root term) — issue early, independent.
        const float vj = fok ? vec_b[j * FD + lane] : 0.f;

        // adj row j: 4 independent 256B coalesced chunk loads.
        const float* rp = adj_b + j * NN;
        const float c0 = rp[lane], c1 = rp[64 + lane], c2 = rp[128 + lane], c3 = rp[192 + lane];
        const unsigned long long m0 = __ballot(c0 != 0.f);
        const unsigned long long m1 = __ballot(c1 != 0.f);
        const unsigned long long m2 = __ballot(c2 != 0.f);
        const unsigned long long m3 = __ballot(c3 != 0.f);
        const int n0 = __popcll(m0), n1 = __popcll(m1), n2 = __popcll(m2), n3 = __popcll(m3);
        const int s01 = n0 + n1, s012 = s01 + n2;
        const int nnz = s012 + n3;               // ~13.6 avg; <=64 w.h.p.

        // In-register rank-select: lane l -> position of the l-th set bit
        // across (m0,m1,m2,m3); also extract a_l = row value at that bit.
        unsigned long long mm; int r, koff;
        if (lane < n0)        { mm = m0; r = lane;        koff = 0;   }
        else if (lane < s01)  { mm = m1; r = lane - n0;   koff = 64;  }
        else if (lane < s012) { mm = m2; r = lane - s01;  koff = 128; }
        else                  { mm = m3; r = lane - s012; koff = 192; }
        int pos = 0;
        #pragma unroll
        for (int w = 32; w >= 1; w >>= 1) {
            const int c = __popcll(mm & (((1ull << w) - 1) << pos));
            if (r >= c) { r -= c; pos += w; }
        }
        const int kl = koff + pos;               // k-index owned by this lane
        const float t0 = __shfl(c0, pos), t1 = __shfl(c1, pos);
        const float t2 = __shfl(c2, pos), t3 = __shfl(c3, pos);
        const float al = (koff == 0) ? t0 : (koff == 64) ? t1 : (koff == 128) ? t2 : t3;

        // Gather vec rows in batches of 8 INDEPENDENT loads (deep MLP).
        float agg = 0.f;
        const int nit = (nnz + 7) >> 3;
        for (int it = 0; it < nit; ++it) {
            const int ib = it << 3;
            int   kk[8]; float aa[8]; float vv[8];
            #pragma unroll
            for (int u = 0; u < 8; ++u) {
                const int idx = ib + u;
                const int   k = __shfl(kl, idx);
                const float a = __shfl(al, idx);
                const bool ok = (idx < nnz);
                kk[u] = ok ? k : 0;
                aa[u] = ok ? a : 0.f;
            }
            #pragma unroll
            for (int u = 0; u < 8; ++u)
                vv[u] = fok ? vec_b[kk[u] * FD + lane] : 0.f;   // 8 in flight
            #pragma unroll
            for (int u = 0; u < 8; ++u)
                agg += aa[u] * vv[u];
        }

        // Layer 1: x[d=lane] = relu(agg @ w1_rel + vec_j @ w1_root + b1).
        float accR = 0.f, accO = 0.f;
        #pragma unroll
        for (int ff = 0; ff < FD; ++ff) {
            accR += __shfl(agg, ff) * s_w1rel[ff * DM + lane];
            accO += __shfl(vj,  ff) * s_w1root[ff * DM + lane];
        }
        const float x = fmaxf(accR + accO + rb1, 0.f);
        accY += a0 * x;
        if (j == 0) x0r = x;
    }

    // ---- cross-wave reduction of accY and x0
    s_pA[q][lane] = accY;
    s_pB[q][lane] = x0r;
    __syncthreads();
    if (q == 0) {
        s_rA[lane] = s_pA[0][lane] + s_pA[1][lane] + s_pA[2][lane] + s_pA[3][lane];
        s_rB[lane] = s_pB[0][lane] + s_pB[1][lane] + s_pB[2][lane] + s_pB[3][lane];
    }
    __syncthreads();

    // ---- layer 2 row 0: y0 = relu(accY @ w2_rel + x0 @ w2_root + b2)
    {
        float p = 0.f;
        const int f0 = q * 16;
        #pragma unroll
        for (int ff2 = 0; ff2 < 16; ++ff2) {
            const int ff = f0 + ff2;
            p += s_rA[ff] * w2_rel[ff * DM + lane]    // f32, L2-resident
               + s_rB[ff] * w2_root[ff * DM + lane];
        }
        s_pA[q][lane] = p;
    }
    __syncthreads();
    if (t < DM) {
        float y = fmaxf(s_pA[0][t] + s_pA[1][t] + s_pA[2][t] + s_pA[3][t] + b2[t], 0.f);
        s_r[t] = s_rB[t] + y;                         // x0 + y0
    }
    __syncthreads();
    if (t < 2) {
        float acc = bf[t];
        #pragma unroll
        for (int d = 0; d < DM; ++d) acc += s_r[d] * wf[d * 2 + t];
        out[b * 2 + t] = acc;
    }
}

extern "C" void kernel_launch(void* const* d_in, const int* in_sizes, int n_in,
                              void* d_out, int out_size, void* d_ws, size_t ws_size,
                              hipStream_t stream) {
    const float* adj     = (const float*)d_in[0];
    const float* vec     = (const float*)d_in[1];
    const float* w1_rel  = (const float*)d_in[2];
    const float* w1_root = (const float*)d_in[3];
    const float* b1      = (const float*)d_in[4];
    const float* w2_rel  = (const float*)d_in[5];
    const float* w2_root = (const float*)d_in[6];
    const float* b2      = (const float*)d_in[7];
    const float* wf      = (const float*)d_in[8];
    const float* bf      = (const float*)d_in[9];
    float* out = (float*)d_out;

    gnn_node0_fused<<<NB, 256, 0, stream>>>(adj, vec, w1_rel, w1_root, b1,
                                            w2_rel, w2_root, b2, wf, bf, out);
}

// Round 7
// 380.199 us; speedup vs baseline: 1.3311x; 1.1771x over previous
//
#include <hip/hip_runtime.h>

// B=1024, N=256, F=63, D=64. Only node-0 readout matters:
//   out = (x[:,0] + y[:,0]) @ wf + bf
// v7: MFMA formulation. Per batch (1 block, 4 waves):
//   stage1: Agg[32][64] = AdjSub[32x256] @ vec[256x64]      (64 MFMA 16x16x32)
//   stage2: X[32][64] = relu(Agg@W1rel + Vsel@W1root + b1)  (32 MFMA)
//   epilogue: accY = a0.X (in-fragment), layer-2 row 0 + head (VALU, tiny).
// Kills v1-v6's disease: per-pair serial readlane/LDS chains (~500 instr/pair
// x 14K pairs at LDS latency). A/B frags use identical k-slot maps (k-perm
// ambiguity cancels); C/D layout is the m89-verified one. All B-frags are
// aligned ds_read_b128 from transposed LDS copies. LDS 75 KB -> 2 blocks/CU.

#define NB 1024
#define NN 256
#define FD 63
#define DM 64
#define MAXP 32
#define VT 264   // s_vecT/s_adj row stride (shorts): 528 B, 16B-aligned, bank-spread
#define W72 72   // 144 B rows, 16B-aligned

using short8 = __attribute__((ext_vector_type(8))) short;
using f32x4  = __attribute__((ext_vector_type(4))) float;

__device__ __forceinline__ short f2bf(float f) {
    unsigned u = __builtin_bit_cast(unsigned, f);
    unsigned r = (u + 0x7FFFu + ((u >> 16) & 1u)) >> 16;
    return (short)r;
}
__device__ __forceinline__ float bf2f(short s) {
    return __builtin_bit_cast(float, ((unsigned)(unsigned short)s) << 16);
}

__launch_bounds__(256, 2)
__global__ void gnn_node0_mfma(const float* __restrict__ adj,
                               const float* __restrict__ vec,
                               const float* __restrict__ w1_rel,
                               const float* __restrict__ w1_root,
                               const float* __restrict__ b1,
                               const float* __restrict__ w2_rel,
                               const float* __restrict__ w2_root,
                               const float* __restrict__ b2,
                               const float* __restrict__ wf,
                               const float* __restrict__ bf,
                               float* __restrict__ out)
{
    __shared__ __align__(16) short s_vecT[DM * VT];      // vec^T [f][k], 33.8 KB
    __shared__ __align__(16) short s_adj[MAXP * VT];     // neighbor adj rows, 16.9 KB
    __shared__ __align__(16) short s_aggb[MAXP * W72];   // Agg bf16, 4.6 KB
    __shared__ __align__(16) short s_w1relT[DM * W72];   // W1rel^T [d][f'], 9.2 KB
    __shared__ __align__(16) short s_w1rootT[DM * W72];  // 9.2 KB
    __shared__ float s_accp[4][DM];
    __shared__ float s_rA[DM], s_rB[DM], s_r[DM];
    __shared__ float s_pA[4][DM];
    __shared__ float s_a0[MAXP];
    __shared__ int   s_nbr[MAXP];
    __shared__ int   s_cnt, s_p0;

    const int b    = blockIdx.x;
    const int t    = threadIdx.x;
    const int lane = t & 63;
    const int q    = t >> 6;
    const int lr   = lane & 15;        // row/col within 16-tile
    const int lg   = lane >> 4;        // k-group
    const int mt   = q & 1;            // wave's M-tile (rows 16*mt..)
    const int ntb  = (q >> 1) * 2;     // wave's two N-tiles
    const float* adj_b = adj + (size_t)b * NN * NN;
    const float* vec_b = vec + (size_t)b * NN * FD;

    if (t == 0) { s_cnt = 0; s_p0 = 0; }
    if (t < MAXP) { s_a0[t] = 0.f; s_nbr[t] = 0; }
    __syncthreads();                                          // B1

    // ---- node-0 neighbor compaction (unordered; sums commute)
    {
        float a = adj_b[t];
        if (a != 0.f) {
            int idx = atomicAdd(&s_cnt, 1);
            if (idx < MAXP) { s_nbr[idx] = t; s_a0[idx] = a; if (t == 0) s_p0 = idx; }
        }
    }
    // ---- stage W1^T (bf16) with zero row f'=63
    for (int i = t; i < FD * DM; i += 256) {
        const int k = i >> 6, d = i & 63;
        s_w1relT[d * W72 + k]  = f2bf(w1_rel[i]);
        s_w1rootT[d * W72 + k] = f2bf(w1_root[i]);
    }
    if (t < DM) { s_w1relT[t * W72 + 63] = 0; s_w1rootT[t * W72 + 63] = 0; }
    // ---- stage vec^T (bf16): wave q stages rows k = 4r+q; row f=63 zeroed
    #pragma unroll 4
    for (int r = 0; r < 64; ++r) {
        const int k = r * 4 + q;
        if (lane < FD) s_vecT[lane * VT + k] = f2bf(vec_b[k * FD + lane]);
    }
    for (int i = t; i < VT; i += 256) s_vecT[63 * VT + i] = 0;
    __syncthreads();                                          // B2

    const int cnt = min(s_cnt, MAXP);
    const int p0  = s_p0;

    // ---- stage neighbor adj rows (bf16), zero-fill p >= cnt
    for (int p = 0; p < MAXP; ++p) {
        if (p < cnt) {
            const int j = s_nbr[p];
            s_adj[p * VT + t] = f2bf(adj_b[j * NN + t]);
        } else {
            s_adj[p * VT + t] = 0;
        }
    }
    __syncthreads();                                          // B3

    // ---- stage 1: Agg[32][64] = AdjSub @ vec  (wave: mt x {ntb, ntb+1})
    {
        f32x4 acc0 = {0.f, 0.f, 0.f, 0.f};
        f32x4 acc1 = {0.f, 0.f, 0.f, 0.f};
        const short* arow = &s_adj[(lr + 16 * mt) * VT];
        const short* brow0 = &s_vecT[(lr + 16 * ntb) * VT];
        const short* brow1 = &s_vecT[(lr + 16 * ntb + 16) * VT];
        #pragma unroll
        for (int ks = 0; ks < 8; ++ks) {
            const int ko = ks * 32 + lg * 8;
            const short8 av = *reinterpret_cast<const short8*>(arow + ko);
            const short8 b0 = *reinterpret_cast<const short8*>(brow0 + ko);
            const short8 b1v = *reinterpret_cast<const short8*>(brow1 + ko);
            acc0 = __builtin_amdgcn_mfma_f32_16x16x32_bf16(av, b0, acc0, 0, 0, 0);
            acc1 = __builtin_amdgcn_mfma_f32_16x16x32_bf16(av, b1v, acc1, 0, 0, 0);
        }
        // C/D layout (m89): col = lane&15, row = (lane>>4)*4 + reg
        #pragma unroll
        for (int r = 0; r < 4; ++r) {
            const int row = lg * 4 + r + 16 * mt;
            s_aggb[row * W72 + lr + 16 * ntb]      = f2bf(acc0[r]);
            s_aggb[row * W72 + lr + 16 * ntb + 16] = f2bf(acc1[r]);
        }
    }
    __syncthreads();                                          // B4

    // ---- stage 2: X = relu(Agg@W1rel + Vsel@W1root + b1); in-fragment epilogue
    {
        f32x4 acc0 = {0.f, 0.f, 0.f, 0.f};
        f32x4 acc1 = {0.f, 0.f, 0.f, 0.f};
        const int prow = lr + 16 * mt;                 // this lane's A-row (pair slot)
        const int jsel = s_nbr[prow];                  // 0 if slot empty (zero-init)
        const short* aggrow = &s_aggb[prow * W72];
        const short* bR0 = &s_w1relT[(lr + 16 * ntb) * W72];
        const short* bR1 = &s_w1relT[(lr + 16 * ntb + 16) * W72];
        const short* bO0 = &s_w1rootT[(lr + 16 * ntb) * W72];
        const short* bO1 = &s_w1rootT[(lr + 16 * ntb + 16) * W72];
        #pragma unroll
        for (int ks = 0; ks < 2; ++ks) {
            const int ko = ks * 32 + lg * 8;
            const short8 aA = *reinterpret_cast<const short8*>(aggrow + ko);
            short8 aV;
            #pragma unroll
            for (int u = 0; u < 8; ++u)                // Vsel[prow][f] = vecT[f][jsel]
                aV[u] = s_vecT[(ko + u) * VT + jsel];  // f=63 row is zeros
            const short8 vR0 = *reinterpret_cast<const short8*>(bR0 + ko);
            const short8 vR1 = *reinterpret_cast<const short8*>(bR1 + ko);
            const short8 vO0 = *reinterpret_cast<const short8*>(bO0 + ko);
            const short8 vO1 = *reinterpret_cast<const short8*>(bO1 + ko);
            acc0 = __builtin_amdgcn_mfma_f32_16x16x32_bf16(aA, vR0, acc0, 0, 0, 0);
            acc0 = __builtin_amdgcn_mfma_f32_16x16x32_bf16(aV, vO0, acc0, 0, 0, 0);
            acc1 = __builtin_amdgcn_mfma_f32_16x16x32_bf16(aA, vR1, acc1, 0, 0, 0);
            acc1 = __builtin_amdgcn_mfma_f32_16x16x32_bf16(aV, vO1, acc1, 0, 0, 0);
        }
        const int c0 = lr + 16 * ntb, c1 = c0 + 16;
        const float bc0 = b1[c0], bc1 = b1[c1];
        float aY0 = 0.f, aY1 = 0.f;
        #pragma unroll
        for (int r = 0; r < 4; ++r) {
            const int row = lg * 4 + r + 16 * mt;      // pair slot of this C-elem
            const float a0 = s_a0[row];                // 0 for empty slots
            const float x0v = fmaxf(acc0[r] + bc0, 0.f);
            const float x1v = fmaxf(acc1[r] + bc1, 0.f);
            aY0 += a0 * x0v;
            aY1 += a0 * x1v;
            if (row == p0) { s_rB[c0] = x0v; s_rB[c1] = x1v; }  // x[b,0]
        }
        // reduce partial accY across the 4 k-groups (lanes differing in bits 4-5)
        aY0 += __shfl_xor(aY0, 16); aY0 += __shfl_xor(aY0, 32);
        aY1 += __shfl_xor(aY1, 16); aY1 += __shfl_xor(aY1, 32);
        if (lg == 0) { s_accp[q][c0] = aY0; s_accp[q][c1] = aY1; }
    }
    __syncthreads();                                          // B5

    // ---- accY = sum over the mt-pair of waves covering this column
    if (q == 0) {
        const int qp = 2 * (lane >> 5);
        s_rA[lane] = s_accp[qp][lane] + s_accp[qp + 1][lane];
    }
    __syncthreads();                                          // B6

    // ---- layer 2 row 0: y0 = relu(accY@w2_rel + x0@w2_root + b2), 4-wave split
    {
        float p = 0.f;
        const int f0 = q * 16;
        #pragma unroll
        for (int ff2 = 0; ff2 < 16; ++ff2) {
            const int ff = f0 + ff2;
            p += s_rA[ff] * w2_rel[ff * DM + lane]
               + s_rB[ff] * w2_root[ff * DM + lane];
        }
        s_pA[q][lane] = p;
    }
    __syncthreads();                                          // B7
    if (t < DM) {
        const float y = fmaxf(s_pA[0][t] + s_pA[1][t] + s_pA[2][t] + s_pA[3][t] + b2[t], 0.f);
        s_r[t] = s_rB[t] + y;                          // x0 + y0
    }
    __syncthreads();                                          // B8
    if (t < 2) {
        float acc = bf[t];
        #pragma unroll
        for (int d = 0; d < DM; ++d) acc += s_r[d] * wf[d * 2 + t];
        out[b * 2 + t] = acc;
    }
}

extern "C" void kernel_launch(void* const* d_in, const int* in_sizes, int n_in,
                              void* d_out, int out_size, void* d_ws, size_t ws_size,
                              hipStream_t stream) {
    const float* adj     = (const float*)d_in[0];
    const float* vec     = (const float*)d_in[1];
    const float* w1_rel  = (const float*)d_in[2];
    const float* w1_root = (const float*)d_in[3];
    const float* b1      = (const float*)d_in[4];
    const float* w2_rel  = (const float*)d_in[5];
    const float* w2_root = (const float*)d_in[6];
    const float* b2      = (const float*)d_in[7];
    const float* wf      = (const float*)d_in[8];
    const float* bf      = (const float*)d_in[9];
    float* out = (float*)d_out;

    gnn_node0_mfma<<<NB, 256, 0, stream>>>(adj, vec, w1_rel, w1_root, b1,
                                           w2_rel, w2_root, b2, wf, bf, out);
}

// Round 8
// 357.522 us; speedup vs baseline: 1.4155x; 1.0634x over previous
//
#include <hip/hip_runtime.h>

// B=1024, N=256, F=63, D=64. Only node-0 readout matters:
//   out = (x[:,0] + y[:,0]) @ wf + bf
// v8 = v7 (MFMA formulation) with staging restructured:
//  - adj A-fragments register-prefetched per lane (16 indep float4 loads)
//    right after compaction; latency hides under vec staging. s_adj removed.
//  - W1 pre-packed to MFMA-frag-order bf16 in ws by K0 (L2-hot coalesced
//    dwordx4 reads in stage2). s_w1*T removed.
//  - LDS 75KB -> ~41KB -> 3 blocks/CU; vec^T staging 8-deep + ds_write_b128.
// MFMA A/B frags use identical (lane,u)->k maps (k-perm ambiguity cancels);
// C/D layout is the m89-verified one (col=lane&15, row=(lane>>4)*4+reg).

#define NB 1024
#define NN 256
#define FD 63
#define DM 64
#define MAXP 32
#define VT 264   // s_vecT row stride (shorts): 528B, 16B-aligned, 8-bank spread
#define W72 72   // s_aggb row stride (shorts): 144B, 16B-aligned

using short8 = __attribute__((ext_vector_type(8))) short;
using f32x4  = __attribute__((ext_vector_type(4))) float;

__device__ __forceinline__ short f2bf(float f) {
    unsigned u = __builtin_bit_cast(unsigned, f);
    return (short)((u + 0x7FFFu + ((u >> 16) & 1u)) >> 16);   // RNE
}

// K0: pack W1rel/W1root into MFMA B-fragment order (bf16), k=63 slot zeroed.
// Element (nt,ks,lane,u) = w1[k][n], n=(lane&15)+16*nt, k=ks*32+(lane>>4)*8+u.
__global__ void k0_w1frag(const float* __restrict__ w1_rel,
                          const float* __restrict__ w1_root,
                          short8* __restrict__ outR,
                          short8* __restrict__ outO)
{
    const int fi = blockIdx.x * blockDim.x + threadIdx.x;   // 0..511
    if (fi >= 512) return;
    const int lane = fi & 63, ksn = fi >> 6;
    const int ks = ksn & 1, nt = ksn >> 1;
    const int n  = (lane & 15) + 16 * nt;
    const int kb = ks * 32 + (lane >> 4) * 8;
    short8 r, o;
    #pragma unroll
    for (int u = 0; u < 8; ++u) {
        const int k = kb + u;
        const bool ok = (k < FD);
        r[u] = ok ? f2bf(w1_rel[k * DM + n])  : (short)0;
        o[u] = ok ? f2bf(w1_root[k * DM + n]) : (short)0;
    }
    outR[fi] = r;
    outO[fi] = o;
}

__launch_bounds__(256, 3)
__global__ void gnn_node0_mfma(const float* __restrict__ adj,
                               const float* __restrict__ vec,
                               const float* __restrict__ b1,
                               const float* __restrict__ w2_rel,
                               const float* __restrict__ w2_root,
                               const float* __restrict__ b2,
                               const float* __restrict__ wf,
                               const float* __restrict__ bf,
                               const short8* __restrict__ w1fR,
                               const short8* __restrict__ w1fO,
                               float* __restrict__ out)
{
    __shared__ __align__(16) short s_vecT[DM * VT];      // vec^T [f][k] bf16, 33.8 KB
    __shared__ __align__(16) short s_aggb[MAXP * W72];   // Agg bf16, 4.6 KB
    __shared__ float s_accp[4][DM];
    __shared__ float s_pA[4][DM];
    __shared__ float s_rA[DM], s_rB[DM], s_r[DM];
    __shared__ float s_a0[MAXP];
    __shared__ int   s_nbr[MAXP];
    __shared__ int   s_cnt, s_p0;

    const int b    = blockIdx.x;
    const int t    = threadIdx.x;
    const int lane = t & 63;
    const int q    = t >> 6;
    const int lr   = lane & 15;        // row/col within 16-tile
    const int lg   = lane >> 4;        // k-group
    const int mt   = q & 1;            // wave's M-tile
    const int ntb  = (q >> 1) * 2;     // wave's two N-tiles
    const float* adj_b = adj + (size_t)b * NN * NN;
    const float* vec_b = vec + (size_t)b * NN * FD;

    if (t == 0) { s_cnt = 0; s_p0 = 0; }
    if (t < MAXP) { s_a0[t] = 0.f; s_nbr[t] = 0; }
    __syncthreads();                                          // B0

    // ---- node-0 neighbor compaction (unordered; sums commute)
    {
        float a = adj_b[t];
        if (a != 0.f) {
            int idx = atomicAdd(&s_cnt, 1);
            if (idx < MAXP) { s_nbr[idx] = t; s_a0[idx] = a; if (t == 0) s_p0 = idx; }
        }
    }
    __syncthreads();                                          // B1

    // ---- A-prefetch: lane's adj row = s_nbr[lr+16*mt]; 16 independent float4
    // loads (k = ks*32 + lg*8 .. +8). Empty slots load row 0 (masked by a0=0).
    const int jmine = s_nbr[lr + 16 * mt];
    f32x4 araw[16];
    {
        const float* rp = adj_b + (size_t)jmine * NN + lg * 8;
        #pragma unroll
        for (int ks = 0; ks < 8; ++ks) {
            araw[2 * ks]     = *reinterpret_cast<const f32x4*>(rp + ks * 32);
            araw[2 * ks + 1] = *reinterpret_cast<const f32x4*>(rp + ks * 32 + 4);
        }
    }

    // ---- vec^T staging: wave q stages k in [q*64, q*64+64); 8 loads in
    // flight per batch; one ds_write_b128 per 8 bf16.
    if (lane < FD) {
        const int kb0 = q * 64;
        #pragma unroll 2
        for (int r0 = 0; r0 < 64; r0 += 8) {
            float v[8];
            #pragma unroll
            for (int u = 0; u < 8; ++u) v[u] = vec_b[(kb0 + r0 + u) * FD + lane];
            short8 sv;
            #pragma unroll
            for (int u = 0; u < 8; ++u) sv[u] = f2bf(v[u]);
            *reinterpret_cast<short8*>(&s_vecT[lane * VT + kb0 + r0]) = sv;
        }
    }
    for (int i = t; i < NN; i += 256) s_vecT[63 * VT + i] = 0;  // zero f=63 row

    // ---- convert A to bf16 fragments (loads have landed under staging)
    short8 afrag[8];
    #pragma unroll
    for (int ks = 0; ks < 8; ++ks) {
        short8 s;
        #pragma unroll
        for (int u = 0; u < 4; ++u) {
            s[u]     = f2bf(araw[2 * ks][u]);
            s[4 + u] = f2bf(araw[2 * ks + 1][u]);
        }
        afrag[ks] = s;
    }
    __syncthreads();                                          // B2

    const int p0 = s_p0;

    // ---- stage 1: Agg[32][64] = AdjSub @ vec  (wave: mt x {ntb, ntb+1})
    {
        f32x4 acc0 = {0.f, 0.f, 0.f, 0.f};
        f32x4 acc1 = {0.f, 0.f, 0.f, 0.f};
        const short* b0p = &s_vecT[(lr + 16 * ntb) * VT + lg * 8];
        const short* b1p = &s_vecT[(lr + 16 * ntb + 16) * VT + lg * 8];
        #pragma unroll
        for (int ks = 0; ks < 8; ++ks) {
            const short8 bf0 = *reinterpret_cast<const short8*>(b0p + ks * 32);
            const short8 bf1 = *reinterpret_cast<const short8*>(b1p + ks * 32);
            acc0 = __builtin_amdgcn_mfma_f32_16x16x32_bf16(afrag[ks], bf0, acc0, 0, 0, 0);
            acc1 = __builtin_amdgcn_mfma_f32_16x16x32_bf16(afrag[ks], bf1, acc1, 0, 0, 0);
        }
        // C/D layout (m89): col = lane&15, row = (lane>>4)*4 + reg
        #pragma unroll
        for (int r = 0; r < 4; ++r) {
            const int row = lg * 4 + r + 16 * mt;
            s_aggb[row * W72 + lr + 16 * ntb]      = f2bf(acc0[r]);
            s_aggb[row * W72 + lr + 16 * ntb + 16] = f2bf(acc1[r]);
        }
    }
    __syncthreads();                                          // B3

    // ---- stage 2: X = relu(Agg@W1rel + Vsel@W1root + b1); epilogue in-frag
    {
        f32x4 acc0 = {0.f, 0.f, 0.f, 0.f};
        f32x4 acc1 = {0.f, 0.f, 0.f, 0.f};
        const int prow = lr + 16 * mt;                 // this lane's pair slot
        const int jsel = s_nbr[prow];                  // 0 if slot empty
        const short* aggrow = &s_aggb[prow * W72 + lg * 8];
        #pragma unroll
        for (int ks = 0; ks < 2; ++ks) {
            const int ko = ks * 32 + lg * 8;
            const short8 aA = *reinterpret_cast<const short8*>(aggrow + ks * 32);
            short8 aV;
            #pragma unroll
            for (int u = 0; u < 8; ++u)                // Vsel[prow][f] = vecT[f][jsel]
                aV[u] = s_vecT[(ko + u) * VT + jsel];  // f=63 row is zeros
            const short8 vR0 = w1fR[((ntb    ) * 2 + ks) * 64 + lane];
            const short8 vR1 = w1fR[((ntb + 1) * 2 + ks) * 64 + lane];
            const short8 vO0 = w1fO[((ntb    ) * 2 + ks) * 64 + lane];
            const short8 vO1 = w1fO[((ntb + 1) * 2 + ks) * 64 + lane];
            acc0 = __builtin_amdgcn_mfma_f32_16x16x32_bf16(aA, vR0, acc0, 0, 0, 0);
            acc0 = __builtin_amdgcn_mfma_f32_16x16x32_bf16(aV, vO0, acc0, 0, 0, 0);
            acc1 = __builtin_amdgcn_mfma_f32_16x16x32_bf16(aA, vR1, acc1, 0, 0, 0);
            acc1 = __builtin_amdgcn_mfma_f32_16x16x32_bf16(aV, vO1, acc1, 0, 0, 0);
        }
        const int c0 = lr + 16 * ntb, c1 = c0 + 16;
        const float bc0 = b1[c0], bc1 = b1[c1];
        float aY0 = 0.f, aY1 = 0.f;
        #pragma unroll
        for (int r = 0; r < 4; ++r) {
            const int row = lg * 4 + r + 16 * mt;      // pair slot of this C-elem
            const float a0 = s_a0[row];                // 0 for empty slots
            const float x0v = fmaxf(acc0[r] + bc0, 0.f);
            const float x1v = fmaxf(acc1[r] + bc1, 0.f);
            aY0 += a0 * x0v;
            aY1 += a0 * x1v;
            if (row == p0) { s_rB[c0] = x0v; s_rB[c1] = x1v; }  // x[b,0]
        }
        // reduce partial accY across the 4 k-groups (lane bits 4-5)
        aY0 += __shfl_xor(aY0, 16); aY0 += __shfl_xor(aY0, 32);
        aY1 += __shfl_xor(aY1, 16); aY1 += __shfl_xor(aY1, 32);
        if (lg == 0) { s_accp[q][c0] = aY0; s_accp[q][c1] = aY1; }
    }
    __syncthreads();                                          // B4

    // ---- accY = sum over the mt-pair of waves covering this column
    if (q == 0) {
        const int qp = 2 * (lane >> 5);
        s_rA[lane] = s_accp[qp][lane] + s_accp[qp + 1][lane];
    }
    __syncthreads();                                          // B5

    // ---- layer 2 row 0: y0 = relu(accY@w2_rel + x0@w2_root + b2), 4-wave split
    {
        float p = 0.f;
        const int f0 = q * 16;
        #pragma unroll
        for (int ff2 = 0; ff2 < 16; ++ff2) {
            const int ff = f0 + ff2;
            p += s_rA[ff] * w2_rel[ff * DM + lane]
               + s_rB[ff] * w2_root[ff * DM + lane];
        }
        s_pA[q][lane] = p;
    }
    __syncthreads();                                          // B6
    if (t < DM) {
        const float y = fmaxf(s_pA[0][t] + s_pA[1][t] + s_pA[2][t] + s_pA[3][t] + b2[t], 0.f);
        s_r[t] = s_rB[t] + y;                          // x0 + y0
    }
    __syncthreads();                                          // B7
    if (t < 2) {
        float acc = bf[t];
        #pragma unroll
        for (int d = 0; d < DM; ++d) acc += s_r[d] * wf[d * 2 + t];
        out[b * 2 + t] = acc;
    }
}

extern "C" void kernel_launch(void* const* d_in, const int* in_sizes, int n_in,
                              void* d_out, int out_size, void* d_ws, size_t ws_size,
                              hipStream_t stream) {
    const float* adj     = (const float*)d_in[0];
    const float* vec     = (const float*)d_in[1];
    const float* w1_rel  = (const float*)d_in[2];
    const float* w1_root = (const float*)d_in[3];
    const float* b1      = (const float*)d_in[4];
    const float* w2_rel  = (const float*)d_in[5];
    const float* w2_root = (const float*)d_in[6];
    const float* b2      = (const float*)d_in[7];
    const float* wf      = (const float*)d_in[8];
    const float* bf      = (const float*)d_in[9];
    float* out = (float*)d_out;

    short8* wsR = (short8*)d_ws;            // 512 frags (8 KB)
    short8* wsO = wsR + 512;                // 8 KB

    k0_w1frag<<<2, 256, 0, stream>>>(w1_rel, w1_root, wsR, wsO);
    gnn_node0_mfma<<<NB, 256, 0, stream>>>(adj, vec, b1, w2_rel, w2_root,
                                           b2, wf, bf, wsR, wsO, out);
}